// Round 1
// baseline (361.402 us; speedup 1.0000x reference)
//
#include <hip/hip_runtime.h>
#include <math.h>

#define BB 2
#define MM 4096
#define NN 8192
#define CC 512
#define NC 20
#define OUTD 512
#define H1 128
#define H2 256
#define CIN 532      // C + NC
#define CPAD 536     // comb row stride (multiple of 4)
#define HPAD 260
#define KNN 3
#define SPLIT 8
#define CHUNK (MM / SPLIT)   // 512
#define DR 16                // rows per block in up_kernel

// ---------------- Kernel A: semantic MLP + softmax probs ----------------
// grid: (B*M/8) blocks x 128 threads
__global__ __launch_bounds__(128) void sem_kernel(
    const float* __restrict__ feat,            // [B*M, C]
    const float* __restrict__ w1g, const float* __restrict__ b1g,
    const float* __restrict__ w2g, const float* __restrict__ b2g,
    float* __restrict__ logits_out,            // [B*M, NC]
    float* __restrict__ P)                     // [B*M, NC] softmax probs
{
    __shared__ float sfeat[8][CC];
    __shared__ float shid[8][H1];
    __shared__ float slg[8][NC];
    const int tid = threadIdx.x;
    const int row0 = blockIdx.x * 8;

    for (int i = tid; i < 8 * CC; i += 128) {
        int r = i >> 9, c = i & (CC - 1);
        sfeat[r][c] = feat[(size_t)(row0 + r) * CC + c];
    }
    __syncthreads();

    float acc[8];
    float bb = b1g[tid];
#pragma unroll
    for (int r = 0; r < 8; ++r) acc[r] = bb;
    for (int c = 0; c < CC; c += 4) {
        float w0 = w1g[(c + 0) * H1 + tid];
        float w1 = w1g[(c + 1) * H1 + tid];
        float w2 = w1g[(c + 2) * H1 + tid];
        float w3 = w1g[(c + 3) * H1 + tid];
#pragma unroll
        for (int r = 0; r < 8; ++r) {
            float4 a = *(const float4*)&sfeat[r][c];
            acc[r] += a.x * w0 + a.y * w1 + a.z * w2 + a.w * w3;
        }
    }
#pragma unroll
    for (int r = 0; r < 8; ++r) shid[r][tid] = fmaxf(acc[r], 0.0f);
    __syncthreads();

    // layer 2: 8*20 = 160 dot products of length 128
    for (int u = tid; u < 8 * NC; u += 128) {
        int r = u / NC, nc = u % NC;
        float a = b2g[nc];
        for (int c = 0; c < H1; ++c) a += shid[r][c] * w2g[c * NC + nc];
        slg[r][nc] = a;
        logits_out[(size_t)(row0 + r) * NC + nc] = a;
    }
    __syncthreads();

    if (tid < 8) {
        int r = tid;
        float mx = -1e30f;
        for (int nc = 0; nc < NC; ++nc) mx = fmaxf(mx, slg[r][nc]);
        float s = 0.0f;
        float e[NC];
#pragma unroll
        for (int nc = 0; nc < NC; ++nc) { e[nc] = __expf(slg[r][nc] - mx); s += e[nc]; }
        float inv = 1.0f / s;
#pragma unroll
        for (int nc = 0; nc < NC; ++nc)
            P[(size_t)(row0 + r) * NC + nc] = e[nc] * inv;
    }
}

// ---------------- Kernel B: partial kNN over an M-chunk ----------------
// grid: (B*N/256, SPLIT) x 256 threads
__global__ __launch_bounds__(256) void knn_partial(
    const float* __restrict__ srcp,    // [B*M, 3]
    const float* __restrict__ tgtp,    // [B*N, 3]
    float* __restrict__ pd2, int* __restrict__ pidx)
{
    __shared__ float sp[CHUNK * 3];
    const int tid = threadIdx.x;
    const int t = blockIdx.x * 256 + tid;      // global tgt idx
    const int b = t >> 13;                     // / 8192
    const int chunk = blockIdx.y;
    const float* spg = srcp + ((size_t)b * MM + (size_t)chunk * CHUNK) * 3;
    for (int i = tid; i < CHUNK * 3; i += 256) sp[i] = spg[i];
    __syncthreads();

    const float tx = tgtp[(size_t)t * 3 + 0];
    const float ty = tgtp[(size_t)t * 3 + 1];
    const float tz = tgtp[(size_t)t * 3 + 2];
    float b0 = 1e30f, b1 = 1e30f, b2 = 1e30f;
    int i0 = 0, i1 = 0, i2 = 0;
    const int mbase = chunk * CHUNK;
#pragma unroll 4
    for (int m = 0; m < CHUNK; ++m) {
        float dx = tx - sp[m * 3 + 0];
        float dy = ty - sp[m * 3 + 1];
        float dz = tz - sp[m * 3 + 2];
        float d2 = dx * dx + dy * dy + dz * dz;
        bool l2 = d2 < b2, l1 = d2 < b1, l0 = d2 < b0;
        // sorted insert (strict < keeps earlier index on exact ties)
        b2 = l1 ? b1 : (l2 ? d2 : b2);
        i2 = l1 ? i1 : (l2 ? (mbase + m) : i2);
        b1 = l0 ? b0 : (l1 ? d2 : b1);
        i1 = l0 ? i0 : (l1 ? (mbase + m) : i1);
        b0 = l0 ? d2 : b0;
        i0 = l0 ? (mbase + m) : i0;
    }
    size_t o = ((size_t)t * SPLIT + chunk) * KNN;
    pd2[o + 0] = b0; pd2[o + 1] = b1; pd2[o + 2] = b2;
    pidx[o + 0] = i0; pidx[o + 1] = i1; pidx[o + 2] = i2;
}

// ---------------- Kernel C: merge partials, softmax(-d) weights ----------------
// grid: (B*N/256) x 256 threads
__global__ __launch_bounds__(256) void knn_merge(
    const float* __restrict__ pd2, const int* __restrict__ pidx,
    float* __restrict__ fw, int* __restrict__ fidx)
{
    const int t = blockIdx.x * 256 + threadIdx.x;
    float b0 = 1e30f, b1 = 1e30f, b2 = 1e30f;
    int i0 = 0, i1 = 0, i2 = 0;
    size_t base = (size_t)t * SPLIT * KNN;
#pragma unroll
    for (int j = 0; j < SPLIT * KNN; ++j) {
        float d2 = pd2[base + j];
        int m = pidx[base + j];
        bool l2 = d2 < b2, l1 = d2 < b1, l0 = d2 < b0;
        b2 = l1 ? b1 : (l2 ? d2 : b2);
        i2 = l1 ? i1 : (l2 ? m : i2);
        b1 = l0 ? b0 : (l1 ? d2 : b1);
        i1 = l0 ? i0 : (l1 ? m : i1);
        b0 = l0 ? d2 : b0;
        i0 = l0 ? m : i0;
    }
    float d0 = sqrtf(fmaxf(b0, 0.0f));
    float d1 = sqrtf(fmaxf(b1, 0.0f));
    float d2s = sqrtf(fmaxf(b2, 0.0f));
    // softmax over (-d0,-d1,-d2); d0 is the max of -d
    float e0 = 1.0f;
    float e1 = __expf(d0 - d1);
    float e2 = __expf(d0 - d2s);
    float inv = 1.0f / (e0 + e1 + e2);
    size_t o = (size_t)t * KNN;
    fw[o + 0] = e0 * inv; fw[o + 1] = e1 * inv; fw[o + 2] = e2 * inv;
    fidx[o + 0] = i0; fidx[o + 1] = i1; fidx[o + 2] = i2;
}

// ---------------- Kernel D: gather + fuse + 2-layer MLP ----------------
// grid: (B*N/DR) x 256 threads
__global__ __launch_bounds__(256) void up_kernel(
    const float* __restrict__ feat,    // [B*M, C]
    const float* __restrict__ P,       // [B*M, NC]
    const int* __restrict__ fidx, const float* __restrict__ fw,
    const float* __restrict__ w1g, const float* __restrict__ b1g,
    const float* __restrict__ w2g, const float* __restrict__ b2g,
    float* __restrict__ out)           // [B*N, OUT]
{
    __shared__ float comb[DR][CPAD];
    __shared__ float hid[DR][HPAD];
    const int tid = threadIdx.x;
    const int row0 = blockIdx.x * DR;

    // gather + fuse into combined rows
    for (int r = 0; r < DR; ++r) {
        int row = row0 + r;
        int b = row >> 13;
        size_t o = (size_t)row * KNN;
        int j0 = fidx[o + 0], j1 = fidx[o + 1], j2 = fidx[o + 2];
        float g0 = fw[o + 0], g1 = fw[o + 1], g2 = fw[o + 2];
        const float* F = feat + (size_t)b * MM * CC;
        const float* f0 = F + (size_t)j0 * CC;
        const float* f1 = F + (size_t)j1 * CC;
        const float* f2 = F + (size_t)j2 * CC;
#pragma unroll
        for (int k = 0; k < 2; ++k) {
            int c = tid + k * 256;
            comb[r][c] = g0 * f0[c] + g1 * f1[c] + g2 * f2[c];
        }
        if (tid < NC) {
            const float* Pb = P + (size_t)b * MM * NC;
            comb[r][CC + tid] = (Pb[(size_t)j0 * NC + tid] +
                                 Pb[(size_t)j1 * NC + tid] +
                                 Pb[(size_t)j2 * NC + tid]) * (1.0f / 3.0f);
        }
    }
    __syncthreads();

    // layer 1: [DR x 532] @ [532 x 256] -> relu
    float acc[DR];
    float bb = b1g[tid];
#pragma unroll
    for (int r = 0; r < DR; ++r) acc[r] = bb;
    for (int c = 0; c < CIN; c += 4) {
        float w0 = w1g[(c + 0) * H2 + tid];
        float w1 = w1g[(c + 1) * H2 + tid];
        float w2 = w1g[(c + 2) * H2 + tid];
        float w3 = w1g[(c + 3) * H2 + tid];
#pragma unroll
        for (int r = 0; r < DR; ++r) {
            float4 a = *(const float4*)&comb[r][c];
            acc[r] += a.x * w0 + a.y * w1 + a.z * w2 + a.w * w3;
        }
    }
#pragma unroll
    for (int r = 0; r < DR; ++r) hid[r][tid] = fmaxf(acc[r], 0.0f);
    __syncthreads();

    // layer 2: [DR x 256] @ [256 x 512]
    float o1[DR], o2[DR];
    float bA = b2g[tid], bB = b2g[tid + 256];
#pragma unroll
    for (int r = 0; r < DR; ++r) { o1[r] = bA; o2[r] = bB; }
    for (int c = 0; c < H2; c += 4) {
        float wA0 = w2g[(c + 0) * OUTD + tid];
        float wA1 = w2g[(c + 1) * OUTD + tid];
        float wA2 = w2g[(c + 2) * OUTD + tid];
        float wA3 = w2g[(c + 3) * OUTD + tid];
        float wB0 = w2g[(c + 0) * OUTD + 256 + tid];
        float wB1 = w2g[(c + 1) * OUTD + 256 + tid];
        float wB2 = w2g[(c + 2) * OUTD + 256 + tid];
        float wB3 = w2g[(c + 3) * OUTD + 256 + tid];
#pragma unroll
        for (int r = 0; r < DR; ++r) {
            float4 h = *(const float4*)&hid[r][c];
            o1[r] += h.x * wA0 + h.y * wA1 + h.z * wA2 + h.w * wA3;
            o2[r] += h.x * wB0 + h.y * wB1 + h.z * wB2 + h.w * wB3;
        }
    }
#pragma unroll
    for (int r = 0; r < DR; ++r) {
        size_t o = (size_t)(row0 + r) * OUTD;
        out[o + tid] = o1[r];
        out[o + 256 + tid] = o2[r];
    }
}

extern "C" void kernel_launch(void* const* d_in, const int* in_sizes, int n_in,
                              void* d_out, int out_size, void* d_ws, size_t ws_size,
                              hipStream_t stream) {
    (void)in_sizes; (void)n_in; (void)out_size; (void)ws_size;
    const float* src_points   = (const float*)d_in[0];
    const float* tgt_points   = (const float*)d_in[1];
    const float* src_features = (const float*)d_in[2];
    const float* w_sem1 = (const float*)d_in[3];
    const float* b_sem1 = (const float*)d_in[4];
    const float* w_sem2 = (const float*)d_in[5];
    const float* b_sem2 = (const float*)d_in[6];
    const float* w_up1  = (const float*)d_in[7];
    const float* b_up1  = (const float*)d_in[8];
    const float* w_up2  = (const float*)d_in[9];
    const float* b_up2  = (const float*)d_in[10];

    float* out    = (float*)d_out;
    float* ups    = out;                                   // [B*N, OUT]
    float* logits = out + (size_t)BB * NN * OUTD;          // [B*M, NC]

    // workspace layout (4 MiB total)
    float* P    = (float*)d_ws;                            // 163840 f
    float* pd2  = P + (size_t)BB * MM * NC;                // 393216 f
    int*   pidx = (int*)(pd2 + (size_t)BB * NN * SPLIT * KNN);
    float* fw   = (float*)(pidx + (size_t)BB * NN * SPLIT * KNN);
    int*   fidx = (int*)(fw + (size_t)BB * NN * KNN);

    sem_kernel<<<dim3(BB * MM / 8), dim3(128), 0, stream>>>(
        src_features, w_sem1, b_sem1, w_sem2, b_sem2, logits, P);
    knn_partial<<<dim3(BB * NN / 256, SPLIT), dim3(256), 0, stream>>>(
        src_points, tgt_points, pd2, pidx);
    knn_merge<<<dim3(BB * NN / 256), dim3(256), 0, stream>>>(pd2, pidx, fw, fidx);
    up_kernel<<<dim3(BB * NN / DR), dim3(256), 0, stream>>>(
        src_features, P, fidx, fw, w_up1, b_up1, w_up2, b_up2, ups);
}

// Round 2
// 229.155 us; speedup vs baseline: 1.5771x; 1.5771x over previous
//
#include <hip/hip_runtime.h>
#include <math.h>

#define BB 2
#define MM 4096
#define NN 8192
#define CC 512
#define NC 20
#define OUTD 512
#define H1 128
#define H2 256
#define CIN 532      // C + NC
#define KNN 3
#define SPLIT 4
#define CHUNK (MM / SPLIT)   // 1024

// MFMA up_kernel geometry
#define RR 32        // rows per block
#define CS1 552      // comb row stride in bf16 (>=544, 16B-aligned rows)
#define HS 264       // hidden row stride in bf16 (16B-aligned rows)
#define KT1 17       // k-tiles layer1 (K=544, pad 532->544 with zeros)
#define KT2 8        // k-tiles layer2 (K=256)

typedef __attribute__((ext_vector_type(8))) short s8;
typedef __attribute__((ext_vector_type(4))) float f4;

__device__ inline unsigned short f2bf(float x) {
    unsigned u = __float_as_uint(x);
    unsigned r = (u + 0x7FFFu + ((u >> 16) & 1u)) >> 16;
    return (unsigned short)r;
}

// ---------------- Kernel A: semantic MLP + softmax probs ----------------
__global__ __launch_bounds__(128) void sem_kernel(
    const float* __restrict__ feat,
    const float* __restrict__ w1g, const float* __restrict__ b1g,
    const float* __restrict__ w2g, const float* __restrict__ b2g,
    float* __restrict__ logits_out, float* __restrict__ P)
{
    __shared__ float sfeat[8][CC];
    __shared__ float shid[8][H1];
    __shared__ float slg[8][NC];
    const int tid = threadIdx.x;
    const int row0 = blockIdx.x * 8;

    for (int i = tid; i < 8 * CC; i += 128) {
        int r = i >> 9, c = i & (CC - 1);
        sfeat[r][c] = feat[(size_t)(row0 + r) * CC + c];
    }
    __syncthreads();

    float acc[8];
    float bb = b1g[tid];
#pragma unroll
    for (int r = 0; r < 8; ++r) acc[r] = bb;
    for (int c = 0; c < CC; c += 4) {
        float w0 = w1g[(c + 0) * H1 + tid];
        float w1 = w1g[(c + 1) * H1 + tid];
        float w2 = w1g[(c + 2) * H1 + tid];
        float w3 = w1g[(c + 3) * H1 + tid];
#pragma unroll
        for (int r = 0; r < 8; ++r) {
            float4 a = *(const float4*)&sfeat[r][c];
            acc[r] += a.x * w0 + a.y * w1 + a.z * w2 + a.w * w3;
        }
    }
#pragma unroll
    for (int r = 0; r < 8; ++r) shid[r][tid] = fmaxf(acc[r], 0.0f);
    __syncthreads();

    for (int u = tid; u < 8 * NC; u += 128) {
        int r = u / NC, nc = u % NC;
        float a = b2g[nc];
        for (int c = 0; c < H1; ++c) a += shid[r][c] * w2g[c * NC + nc];
        slg[r][nc] = a;
        logits_out[(size_t)(row0 + r) * NC + nc] = a;
    }
    __syncthreads();

    if (tid < 8) {
        int r = tid;
        float mx = -1e30f;
        for (int nc = 0; nc < NC; ++nc) mx = fmaxf(mx, slg[r][nc]);
        float s = 0.0f;
        float e[NC];
#pragma unroll
        for (int nc = 0; nc < NC; ++nc) { e[nc] = __expf(slg[r][nc] - mx); s += e[nc]; }
        float inv = 1.0f / s;
#pragma unroll
        for (int nc = 0; nc < NC; ++nc)
            P[(size_t)(row0 + r) * NC + nc] = e[nc] * inv;
    }
}

// ---------------- Kernel B: partial kNN over an M-chunk ----------------
__global__ __launch_bounds__(256) void knn_partial(
    const float* __restrict__ srcp, const float* __restrict__ tgtp,
    float* __restrict__ pd2, int* __restrict__ pidx)
{
    __shared__ float sp[CHUNK * 3];
    const int tid = threadIdx.x;
    const int t = blockIdx.x * 256 + tid;
    const int b = t >> 13;
    const int chunk = blockIdx.y;
    const float* spg = srcp + ((size_t)b * MM + (size_t)chunk * CHUNK) * 3;
    for (int i = tid; i < CHUNK * 3; i += 256) sp[i] = spg[i];
    __syncthreads();

    const float tx = tgtp[(size_t)t * 3 + 0];
    const float ty = tgtp[(size_t)t * 3 + 1];
    const float tz = tgtp[(size_t)t * 3 + 2];
    float b0 = 1e30f, b1 = 1e30f, b2 = 1e30f;
    int i0 = 0, i1 = 0, i2 = 0;
    const int mbase = chunk * CHUNK;
#pragma unroll 4
    for (int m = 0; m < CHUNK; ++m) {
        float dx = tx - sp[m * 3 + 0];
        float dy = ty - sp[m * 3 + 1];
        float dz = tz - sp[m * 3 + 2];
        float d2 = dx * dx + dy * dy + dz * dz;
        bool l2 = d2 < b2, l1 = d2 < b1, l0 = d2 < b0;
        b2 = l1 ? b1 : (l2 ? d2 : b2);
        i2 = l1 ? i1 : (l2 ? (mbase + m) : i2);
        b1 = l0 ? b0 : (l1 ? d2 : b1);
        i1 = l0 ? i0 : (l1 ? (mbase + m) : i1);
        b0 = l0 ? d2 : b0;
        i0 = l0 ? (mbase + m) : i0;
    }
    size_t o = ((size_t)t * SPLIT + chunk) * KNN;
    pd2[o + 0] = b0; pd2[o + 1] = b1; pd2[o + 2] = b2;
    pidx[o + 0] = i0; pidx[o + 1] = i1; pidx[o + 2] = i2;
}

// ---------------- Kernel C: merge partials, softmax(-d) weights ----------------
__global__ __launch_bounds__(256) void knn_merge(
    const float* __restrict__ pd2, const int* __restrict__ pidx,
    float* __restrict__ fw, int* __restrict__ fidx)
{
    const int t = blockIdx.x * 256 + threadIdx.x;
    float b0 = 1e30f, b1 = 1e30f, b2 = 1e30f;
    int i0 = 0, i1 = 0, i2 = 0;
    size_t base = (size_t)t * SPLIT * KNN;
#pragma unroll
    for (int j = 0; j < SPLIT * KNN; ++j) {
        float d2 = pd2[base + j];
        int m = pidx[base + j];
        bool l2 = d2 < b2, l1 = d2 < b1, l0 = d2 < b0;
        b2 = l1 ? b1 : (l2 ? d2 : b2);
        i2 = l1 ? i1 : (l2 ? m : i2);
        b1 = l0 ? b0 : (l1 ? d2 : b1);
        i1 = l0 ? i0 : (l1 ? m : i1);
        b0 = l0 ? d2 : b0;
        i0 = l0 ? m : i0;
    }
    float d0 = sqrtf(fmaxf(b0, 0.0f));
    float d1 = sqrtf(fmaxf(b1, 0.0f));
    float d2s = sqrtf(fmaxf(b2, 0.0f));
    float e0 = 1.0f;
    float e1 = __expf(d0 - d1);
    float e2 = __expf(d0 - d2s);
    float inv = 1.0f / (e0 + e1 + e2);
    size_t o = (size_t)t * KNN;
    fw[o + 0] = e0 * inv; fw[o + 1] = e1 * inv; fw[o + 2] = e2 * inv;
    fidx[o + 0] = i0; fidx[o + 1] = i1; fidx[o + 2] = i2;
}

// ---------------- Kernel P: pack upsample weights to bf16 MFMA-B layout ----------------
// W1p[(kb*256+n)*32+kk] = bf16(w1[(kb*32+kk)*256+n]) (zero for k>=532)
// W2p[(kb*512+n)*32+kk] = bf16(w2[(kb*32+kk)*512+n])
__global__ __launch_bounds__(256) void pack_weights(
    const float* __restrict__ w1, const float* __restrict__ w2,
    unsigned short* __restrict__ w1p, unsigned short* __restrict__ w2p)
{
    int i = blockIdx.x * 256 + threadIdx.x;
    const int total1 = KT1 * H2 * 32;      // 139264
    const int total2 = KT2 * OUTD * 32;    // 131072
    if (i < total1) {
        int kk = i & 31, n = (i >> 5) & 255, kb = i >> 13;
        int k = kb * 32 + kk;
        float v = (k < CIN) ? w1[(size_t)k * H2 + n] : 0.0f;
        w1p[i] = f2bf(v);
    }
    if (i < total2) {
        int kk = i & 31, n = (i >> 5) & 511, kb = i >> 14;
        int k = kb * 32 + kk;
        float v = w2[(size_t)k * OUTD + n];
        w2p[i] = f2bf(v);
    }
}

// ---------------- Kernel D: gather + fuse + bf16-MFMA 2-layer MLP ----------------
// grid: (B*N/RR) x 256 threads (4 waves)
__global__ __launch_bounds__(256) void up_kernel(
    const float* __restrict__ feat, const float* __restrict__ P,
    const int* __restrict__ fidx, const float* __restrict__ fw,
    const unsigned short* __restrict__ w1p, const unsigned short* __restrict__ w2p,
    const float* __restrict__ b1g, const float* __restrict__ b2g,
    float* __restrict__ out)
{
    __shared__ unsigned short comb[RR * CS1];
    __shared__ unsigned short hid[RR * HS];
    const int tid = threadIdx.x;
    const int row0 = blockIdx.x * RR;
    const int lane = tid & 63;
    const int wv = tid >> 6;
    const int l15 = lane & 15;
    const int quad = lane >> 4;

    // ---- gather + fuse: comb[r][0..531] = sum_k g_k * feat[j_k], [532..543]=pad0 ----
    {
        const int r = tid >> 3, p = tid & 7;   // 8 threads per row
        int row = row0 + r;
        int b = row >> 13;
        size_t o = (size_t)row * KNN;
        int j0 = fidx[o], j1 = fidx[o + 1], j2 = fidx[o + 2];
        float g0 = fw[o], g1 = fw[o + 1], g2 = fw[o + 2];
        const float* F = feat + (size_t)b * MM * CC;
        const float4* f0 = (const float4*)(F + (size_t)j0 * CC);
        const float4* f1 = (const float4*)(F + (size_t)j1 * CC);
        const float4* f2 = (const float4*)(F + (size_t)j2 * CC);
#pragma unroll 4
        for (int j = 0; j < 16; ++j) {
            int c4 = j * 8 + p;
            float4 a0 = f0[c4], a1 = f1[c4], a2 = f2[c4];
            ushort4 s;
            s.x = f2bf(g0 * a0.x + g1 * a1.x + g2 * a2.x);
            s.y = f2bf(g0 * a0.y + g1 * a1.y + g2 * a2.y);
            s.z = f2bf(g0 * a0.z + g1 * a1.z + g2 * a2.z);
            s.w = f2bf(g0 * a0.w + g1 * a1.w + g2 * a2.w);
            *(ushort4*)&comb[r * CS1 + c4 * 4] = s;
        }
        const float* Pb = P + (size_t)b * MM * NC;
        if (p < 4) {
            for (int q = p; q < 32; q += 4) {
                unsigned short v = 0;
                if (q < NC)
                    v = f2bf((Pb[(size_t)j0 * NC + q] + Pb[(size_t)j1 * NC + q] +
                              Pb[(size_t)j2 * NC + q]) * (1.0f / 3.0f));
                comb[r * CS1 + 512 + q] = v;
            }
        }
    }
    __syncthreads();

    // ---- layer 1: [32 x 544] @ [544 x 256] -> relu -> hid (bf16) ----
    {
        const int n0 = wv * 64;
        f4 acc1[2][4];
#pragma unroll
        for (int rt = 0; rt < 2; ++rt)
#pragma unroll
            for (int c = 0; c < 4; ++c) acc1[rt][c] = (f4){0.f, 0.f, 0.f, 0.f};

        for (int kb = 0; kb < KT1; ++kb) {
            s8 a0 = *(const s8*)&comb[l15 * CS1 + kb * 32 + quad * 8];
            s8 a1 = *(const s8*)&comb[(l15 + 16) * CS1 + kb * 32 + quad * 8];
            s8 bfr[4];
#pragma unroll
            for (int c = 0; c < 4; ++c)
                bfr[c] = *(const s8*)&w1p[((size_t)(kb * H2 + n0 + c * 16 + l15)) * 32 + quad * 8];
#pragma unroll
            for (int c = 0; c < 4; ++c) {
                acc1[0][c] = __builtin_amdgcn_mfma_f32_16x16x32_bf16(a0, bfr[c], acc1[0][c], 0, 0, 0);
                acc1[1][c] = __builtin_amdgcn_mfma_f32_16x16x32_bf16(a1, bfr[c], acc1[1][c], 0, 0, 0);
            }
        }
#pragma unroll
        for (int c = 0; c < 4; ++c) {
            int ccol = n0 + c * 16 + l15;
            float bias = b1g[ccol];
#pragma unroll
            for (int rt = 0; rt < 2; ++rt)
#pragma unroll
                for (int i = 0; i < 4; ++i) {
                    int rr = rt * 16 + quad * 4 + i;
                    hid[rr * HS + ccol] = f2bf(fmaxf(acc1[rt][c][i] + bias, 0.0f));
                }
        }
    }
    __syncthreads();

    // ---- layer 2: [32 x 256] @ [256 x 512] + bias -> out (fp32) ----
    {
        const int m0 = wv * 128;
        f4 acc2[2][8];
#pragma unroll
        for (int rt = 0; rt < 2; ++rt)
#pragma unroll
            for (int c = 0; c < 8; ++c) acc2[rt][c] = (f4){0.f, 0.f, 0.f, 0.f};

        for (int kb = 0; kb < KT2; ++kb) {
            s8 a0 = *(const s8*)&hid[l15 * HS + kb * 32 + quad * 8];
            s8 a1 = *(const s8*)&hid[(l15 + 16) * HS + kb * 32 + quad * 8];
            s8 bfr[8];
#pragma unroll
            for (int c = 0; c < 8; ++c)
                bfr[c] = *(const s8*)&w2p[((size_t)(kb * OUTD + m0 + c * 16 + l15)) * 32 + quad * 8];
#pragma unroll
            for (int c = 0; c < 8; ++c) {
                acc2[0][c] = __builtin_amdgcn_mfma_f32_16x16x32_bf16(a0, bfr[c], acc2[0][c], 0, 0, 0);
                acc2[1][c] = __builtin_amdgcn_mfma_f32_16x16x32_bf16(a1, bfr[c], acc2[1][c], 0, 0, 0);
            }
        }
#pragma unroll
        for (int c = 0; c < 8; ++c) {
            int ccol = m0 + c * 16 + l15;
            float bias = b2g[ccol];
#pragma unroll
            for (int rt = 0; rt < 2; ++rt)
#pragma unroll
                for (int i = 0; i < 4; ++i) {
                    int rr = rt * 16 + quad * 4 + i;
                    out[(size_t)(row0 + rr) * OUTD + ccol] = acc2[rt][c][i] + bias;
                }
        }
    }
}

extern "C" void kernel_launch(void* const* d_in, const int* in_sizes, int n_in,
                              void* d_out, int out_size, void* d_ws, size_t ws_size,
                              hipStream_t stream) {
    (void)in_sizes; (void)n_in; (void)out_size; (void)ws_size;
    const float* src_points   = (const float*)d_in[0];
    const float* tgt_points   = (const float*)d_in[1];
    const float* src_features = (const float*)d_in[2];
    const float* w_sem1 = (const float*)d_in[3];
    const float* b_sem1 = (const float*)d_in[4];
    const float* w_sem2 = (const float*)d_in[5];
    const float* b_sem2 = (const float*)d_in[6];
    const float* w_up1  = (const float*)d_in[7];
    const float* b_up1  = (const float*)d_in[8];
    const float* w_up2  = (const float*)d_in[9];
    const float* b_up2  = (const float*)d_in[10];

    float* out    = (float*)d_out;
    float* ups    = out;
    float* logits = out + (size_t)BB * NN * OUTD;

    // workspace layout (~3.02 MiB of the 4 MiB proven available)
    float* P    = (float*)d_ws;                                  // 163840 f
    float* pd2  = P + (size_t)BB * MM * NC;                      // 196608 f
    int*   pidx = (int*)(pd2 + (size_t)BB * NN * SPLIT * KNN);   // 196608 i
    float* fw   = (float*)(pidx + (size_t)BB * NN * SPLIT * KNN);// 49152 f
    int*   fidx = (int*)(fw + (size_t)BB * NN * KNN);            // 49152 i
    unsigned short* w1p = (unsigned short*)(fidx + (size_t)BB * NN * KNN); // 139264 us
    unsigned short* w2p = w1p + (size_t)KT1 * H2 * 32;                     // 131072 us

    pack_weights<<<dim3((KT1 * H2 * 32 + 255) / 256), dim3(256), 0, stream>>>(
        w_up1, w_up2, w1p, w2p);
    sem_kernel<<<dim3(BB * MM / 8), dim3(128), 0, stream>>>(
        src_features, w_sem1, b_sem1, w_sem2, b_sem2, logits, P);
    knn_partial<<<dim3(BB * NN / 256, SPLIT), dim3(256), 0, stream>>>(
        src_points, tgt_points, pd2, pidx);
    knn_merge<<<dim3(BB * NN / 256), dim3(256), 0, stream>>>(pd2, pidx, fw, fidx);
    up_kernel<<<dim3(BB * NN / RR), dim3(256), 0, stream>>>(
        src_features, P, fidx, fw, w1p, w2p, b_up1, b_up2, ups);
}

// Round 3
// 195.623 us; speedup vs baseline: 1.8474x; 1.1714x over previous
//
#include <hip/hip_runtime.h>
#include <math.h>

#define BB 2
#define MM 4096
#define NN 8192
#define CC 512
#define NC 20
#define OUTD 512
#define H1 128
#define H2 256
#define CIN 532      // C + NC
#define KNN 3
#define SPLIT 8
#define CHUNK (MM / SPLIT)   // 512

// up_kernel MFMA geometry
#define RR 32        // rows per block
#define CS1 552      // comb row stride in bf16
#define HS 264       // hidden row stride in bf16
#define KT1 17       // k-tiles layer1 (K=544)
#define KT2 8        // k-tiles layer2 (K=256)

// sem_kernel MFMA geometry
#define FS 520       // sfeat stride (bf16), 1040B rows
#define HS2 136      // shid stride (bf16)
#define SKT1 16      // K=512
#define SKT2 4       // K=128

typedef __attribute__((ext_vector_type(8))) short s8;
typedef __attribute__((ext_vector_type(4))) float f4;

__device__ inline unsigned short f2bf(float x) {
    unsigned u = __float_as_uint(x);
    unsigned r = (u + 0x7FFFu + ((u >> 16) & 1u)) >> 16;
    return (unsigned short)r;
}
__device__ inline float bf2f(unsigned short u) {
    return __uint_as_float(((unsigned)u) << 16);
}

// ---------------- Kernel 0: pack sp4 + all bf16 weights ----------------
__global__ __launch_bounds__(256) void prep_kernel(
    const float* __restrict__ srcp,
    const float* __restrict__ wu1, const float* __restrict__ wu2,
    const float* __restrict__ ws1, const float* __restrict__ ws2,
    float4* __restrict__ sp4,
    unsigned short* __restrict__ w1p, unsigned short* __restrict__ w2p,
    unsigned short* __restrict__ ws1p, unsigned short* __restrict__ ws2p)
{
    int i = blockIdx.x * 256 + threadIdx.x;
    if (i < BB * MM) {      // 8192 source points -> (x,y,z,|s|^2)
        float x = srcp[(size_t)i * 3 + 0];
        float y = srcp[(size_t)i * 3 + 1];
        float z = srcp[(size_t)i * 3 + 2];
        sp4[i] = make_float4(x, y, z, x * x + y * y + z * z);
    }
    if (i < KT1 * H2 * 32) {            // 139264: upsample L1
        int kk = i & 31, n = (i >> 5) & 255, kb = i >> 13;
        int k = kb * 32 + kk;
        w1p[i] = f2bf((k < CIN) ? wu1[(size_t)k * H2 + n] : 0.0f);
    }
    if (i < KT2 * OUTD * 32) {          // 131072: upsample L2
        int kk = i & 31, n = (i >> 5) & 511, kb = i >> 14;
        int k = kb * 32 + kk;
        w2p[i] = f2bf(wu2[(size_t)k * OUTD + n]);
    }
    if (i < SKT1 * H1 * 32) {           // 65536: semantic L1
        int kk = i & 31, n = (i >> 5) & 127, kb = i >> 12;
        int k = kb * 32 + kk;
        ws1p[i] = f2bf(ws1[(size_t)k * H1 + n]);
    }
    if (i < SKT2 * 32 * 32) {           // 4096: semantic L2 (N padded 20->32)
        int kk = i & 31, n = (i >> 5) & 31, kb = i >> 10;
        int k = kb * 32 + kk;
        ws2p[i] = f2bf((n < NC) ? ws2[(size_t)k * NC + n] : 0.0f);
    }
}

// ---------------- Kernel A: semantic MLP (bf16 MFMA) + softmax probs ----------------
// grid: B*M/32 blocks x 256 threads
__global__ __launch_bounds__(256) void sem_kernel(
    const float* __restrict__ feat,
    const unsigned short* __restrict__ ws1p, const unsigned short* __restrict__ ws2p,
    const float* __restrict__ b1g, const float* __restrict__ b2g,
    float* __restrict__ logits_out, unsigned short* __restrict__ P)
{
    __shared__ unsigned short sfeat[32 * FS];
    __shared__ unsigned short shid[32 * HS2];
    __shared__ float slg[32][33];
    const int tid = threadIdx.x;
    const int row0 = blockIdx.x * 32;
    const int lane = tid & 63;
    const int wv = tid >> 6;
    const int l15 = lane & 15;
    const int quad = lane >> 4;

    // stage 32 rows of feat as bf16 (8 threads per row)
    {
        const int r = tid >> 3, p = tid & 7;
        const float4* fr = (const float4*)(feat + (size_t)(row0 + r) * CC);
#pragma unroll 4
        for (int j = 0; j < 16; ++j) {
            int c4 = j * 8 + p;
            float4 a = fr[c4];
            ushort4 s;
            s.x = f2bf(a.x); s.y = f2bf(a.y); s.z = f2bf(a.z); s.w = f2bf(a.w);
            *(ushort4*)&sfeat[r * FS + c4 * 4] = s;
        }
    }
    __syncthreads();

    // layer 1: [32 x 512] @ [512 x 128] -> relu -> shid
    {
        const int n0 = wv * 32;
        f4 acc[2][2];
#pragma unroll
        for (int rt = 0; rt < 2; ++rt)
#pragma unroll
            for (int c = 0; c < 2; ++c) acc[rt][c] = (f4){0.f, 0.f, 0.f, 0.f};
        for (int kb = 0; kb < SKT1; ++kb) {
            s8 a0 = *(const s8*)&sfeat[l15 * FS + kb * 32 + quad * 8];
            s8 a1 = *(const s8*)&sfeat[(l15 + 16) * FS + kb * 32 + quad * 8];
#pragma unroll
            for (int c = 0; c < 2; ++c) {
                s8 bf = *(const s8*)&ws1p[((size_t)(kb * H1 + n0 + c * 16 + l15)) * 32 + quad * 8];
                acc[0][c] = __builtin_amdgcn_mfma_f32_16x16x32_bf16(a0, bf, acc[0][c], 0, 0, 0);
                acc[1][c] = __builtin_amdgcn_mfma_f32_16x16x32_bf16(a1, bf, acc[1][c], 0, 0, 0);
            }
        }
#pragma unroll
        for (int c = 0; c < 2; ++c) {
            int col = n0 + c * 16 + l15;
            float bias = b1g[col];
#pragma unroll
            for (int rt = 0; rt < 2; ++rt)
#pragma unroll
                for (int i = 0; i < 4; ++i) {
                    int rr = rt * 16 + quad * 4 + i;
                    shid[rr * HS2 + col] = f2bf(fmaxf(acc[rt][c][i] + bias, 0.0f));
                }
        }
    }
    __syncthreads();

    // layer 2: [32 x 128] @ [128 x 32(20)] ; wave -> (rowtile, coltile)
    {
        const int rt = wv & 1, ct = wv >> 1;
        f4 acc2 = (f4){0.f, 0.f, 0.f, 0.f};
        for (int kb = 0; kb < SKT2; ++kb) {
            s8 a = *(const s8*)&shid[(rt * 16 + l15) * HS2 + kb * 32 + quad * 8];
            s8 bf = *(const s8*)&ws2p[((size_t)(kb * 32 + ct * 16 + l15)) * 32 + quad * 8];
            acc2 = __builtin_amdgcn_mfma_f32_16x16x32_bf16(a, bf, acc2, 0, 0, 0);
        }
        int col = ct * 16 + l15;
        float bias = (col < NC) ? b2g[col] : 0.0f;
#pragma unroll
        for (int i = 0; i < 4; ++i) {
            int rr = rt * 16 + quad * 4 + i;
            float v = acc2[i] + bias;
            slg[rr][col] = v;
            if (col < NC)
                logits_out[(size_t)(row0 + rr) * NC + col] = v;
        }
    }
    __syncthreads();

    if (tid < 32) {
        int r = tid;
        float mx = -1e30f;
        for (int nc = 0; nc < NC; ++nc) mx = fmaxf(mx, slg[r][nc]);
        float s = 0.0f;
        float e[NC];
#pragma unroll
        for (int nc = 0; nc < NC; ++nc) { e[nc] = __expf(slg[r][nc] - mx); s += e[nc]; }
        float inv = 1.0f / s;
#pragma unroll
        for (int nc = 0; nc < NC; ++nc)
            P[(size_t)(row0 + r) * NC + nc] = f2bf(e[nc] * inv);
    }
}

// ---------------- Kernel B: partial kNN, scalar-load + dual insert chains ----------------
// grid: (B*N/256, SPLIT) x 256 threads
__global__ __launch_bounds__(256) void knn_partial(
    const float4* __restrict__ sp4, const float* __restrict__ tgtp,
    float* __restrict__ pd2, unsigned short* __restrict__ pidx)
{
    const int tid = threadIdx.x;
    const int t = blockIdx.x * 256 + tid;
    const int b = t >> 13;
    const int chunk = blockIdx.y;
    const float4* sp = sp4 + (size_t)b * MM + (size_t)chunk * CHUNK;  // uniform base

    const float tx = tgtp[(size_t)t * 3 + 0];
    const float ty = tgtp[(size_t)t * 3 + 1];
    const float tz = tgtp[(size_t)t * 3 + 2];
    const float m2x = -2.0f * tx, m2y = -2.0f * ty, m2z = -2.0f * tz;

    // chain A (even m), chain C (odd m) — independent for ILP
    float a0 = 1e30f, a1 = 1e30f, a2 = 1e30f;
    int ia0 = 0, ia1 = 0, ia2 = 0;
    float c0 = 1e30f, c1 = 1e30f, c2 = 1e30f;
    int ic0 = 0, ic1 = 0, ic2 = 0;
    const int mbase = chunk * CHUNK;

#pragma unroll 2
    for (int m = 0; m < CHUNK; m += 2) {
        float4 p = sp[m];       // uniform index -> scalar loads
        float4 q = sp[m + 1];
        float da = fmaf(m2x, p.x, fmaf(m2y, p.y, fmaf(m2z, p.z, p.w)));
        float dc = fmaf(m2x, q.x, fmaf(m2y, q.y, fmaf(m2z, q.z, q.w)));
        {
            bool l2 = da < a2, l1 = da < a1, l0 = da < a0;
            a2 = l1 ? a1 : (l2 ? da : a2); ia2 = l1 ? ia1 : (l2 ? (mbase + m) : ia2);
            a1 = l0 ? a0 : (l1 ? da : a1); ia1 = l0 ? ia0 : (l1 ? (mbase + m) : ia1);
            a0 = l0 ? da : a0;             ia0 = l0 ? (mbase + m) : ia0;
        }
        {
            bool l2 = dc < c2, l1 = dc < c1, l0 = dc < c0;
            c2 = l1 ? c1 : (l2 ? dc : c2); ic2 = l1 ? ic1 : (l2 ? (mbase + m + 1) : ic2);
            c1 = l0 ? c0 : (l1 ? dc : c1); ic1 = l0 ? ic0 : (l1 ? (mbase + m + 1) : ic1);
            c0 = l0 ? dc : c0;             ic0 = l0 ? (mbase + m + 1) : ic0;
        }
    }
    // merge chain C into chain A with index tie-break (stable top-k semantics)
#pragma unroll
    for (int j = 0; j < 3; ++j) {
        float d = (j == 0) ? c0 : (j == 1) ? c1 : c2;
        int   i = (j == 0) ? ic0 : (j == 1) ? ic1 : ic2;
        bool e2 = (d < a2) || (d == a2 && i < ia2);
        bool e1 = (d < a1) || (d == a1 && i < ia1);
        bool e0 = (d < a0) || (d == a0 && i < ia0);
        a2 = e1 ? a1 : (e2 ? d : a2); ia2 = e1 ? ia1 : (e2 ? i : ia2);
        a1 = e0 ? a0 : (e1 ? d : a1); ia1 = e0 ? ia0 : (e1 ? i : ia1);
        a0 = e0 ? d : a0;             ia0 = e0 ? i : ia0;
    }
    size_t o = ((size_t)t * SPLIT + chunk) * KNN;
    pd2[o + 0] = a0; pd2[o + 1] = a1; pd2[o + 2] = a2;
    pidx[o + 0] = (unsigned short)ia0;
    pidx[o + 1] = (unsigned short)ia1;
    pidx[o + 2] = (unsigned short)ia2;
}

// ---------------- Kernel C: merge partials, softmax(-d) weights ----------------
__global__ __launch_bounds__(256) void knn_merge(
    const float* __restrict__ pd2, const unsigned short* __restrict__ pidx,
    const float* __restrict__ tgtp,
    float* __restrict__ fw, int* __restrict__ fidx)
{
    const int t = blockIdx.x * 256 + threadIdx.x;
    float b0 = 1e30f, b1 = 1e30f, b2 = 1e30f;
    int i0 = 0, i1 = 0, i2 = 0;
    size_t base = (size_t)t * SPLIT * KNN;
#pragma unroll
    for (int j = 0; j < SPLIT * KNN; ++j) {
        float d2 = pd2[base + j];
        int m = pidx[base + j];
        bool l2 = d2 < b2, l1 = d2 < b1, l0 = d2 < b0;
        b2 = l1 ? b1 : (l2 ? d2 : b2);
        i2 = l1 ? i1 : (l2 ? m : i2);
        b1 = l0 ? b0 : (l1 ? d2 : b1);
        i1 = l0 ? i0 : (l1 ? m : i1);
        b0 = l0 ? d2 : b0;
        i0 = l0 ? m : i0;
    }
    const float tx = tgtp[(size_t)t * 3 + 0];
    const float ty = tgtp[(size_t)t * 3 + 1];
    const float tz = tgtp[(size_t)t * 3 + 2];
    const float t2 = tx * tx + ty * ty + tz * tz;
    float d0 = sqrtf(fmaxf(b0 + t2, 0.0f));
    float d1 = sqrtf(fmaxf(b1 + t2, 0.0f));
    float d2s = sqrtf(fmaxf(b2 + t2, 0.0f));
    float e0 = 1.0f;
    float e1 = __expf(d0 - d1);
    float e2 = __expf(d0 - d2s);
    float inv = 1.0f / (e0 + e1 + e2);
    size_t o = (size_t)t * KNN;
    fw[o + 0] = e0 * inv; fw[o + 1] = e1 * inv; fw[o + 2] = e2 * inv;
    fidx[o + 0] = i0; fidx[o + 1] = i1; fidx[o + 2] = i2;
}

// ---------------- Kernel D: gather + fuse + bf16-MFMA 2-layer MLP ----------------
__global__ __launch_bounds__(256) void up_kernel(
    const float* __restrict__ feat, const unsigned short* __restrict__ P,
    const int* __restrict__ fidx, const float* __restrict__ fw,
    const unsigned short* __restrict__ w1p, const unsigned short* __restrict__ w2p,
    const float* __restrict__ b1g, const float* __restrict__ b2g,
    float* __restrict__ out)
{
    __shared__ unsigned short comb[RR * CS1];
    __shared__ unsigned short hid[RR * HS];
    const int tid = threadIdx.x;
    const int row0 = blockIdx.x * RR;
    const int lane = tid & 63;
    const int wv = tid >> 6;
    const int l15 = lane & 15;
    const int quad = lane >> 4;

    {
        const int r = tid >> 3, p = tid & 7;
        int row = row0 + r;
        int b = row >> 13;
        size_t o = (size_t)row * KNN;
        int j0 = fidx[o], j1 = fidx[o + 1], j2 = fidx[o + 2];
        float g0 = fw[o], g1 = fw[o + 1], g2 = fw[o + 2];
        const float* F = feat + (size_t)b * MM * CC;
        const float4* f0 = (const float4*)(F + (size_t)j0 * CC);
        const float4* f1 = (const float4*)(F + (size_t)j1 * CC);
        const float4* f2 = (const float4*)(F + (size_t)j2 * CC);
#pragma unroll 4
        for (int j = 0; j < 16; ++j) {
            int c4 = j * 8 + p;
            float4 a0 = f0[c4], a1 = f1[c4], a2 = f2[c4];
            ushort4 s;
            s.x = f2bf(g0 * a0.x + g1 * a1.x + g2 * a2.x);
            s.y = f2bf(g0 * a0.y + g1 * a1.y + g2 * a2.y);
            s.z = f2bf(g0 * a0.z + g1 * a1.z + g2 * a2.z);
            s.w = f2bf(g0 * a0.w + g1 * a1.w + g2 * a2.w);
            *(ushort4*)&comb[r * CS1 + c4 * 4] = s;
        }
        const unsigned short* Pb = P + (size_t)b * MM * NC;
        if (p < 4) {
            for (int q = p; q < 32; q += 4) {
                unsigned short v = 0;
                if (q < NC)
                    v = f2bf((bf2f(Pb[(size_t)j0 * NC + q]) + bf2f(Pb[(size_t)j1 * NC + q]) +
                              bf2f(Pb[(size_t)j2 * NC + q])) * (1.0f / 3.0f));
                comb[r * CS1 + 512 + q] = v;
            }
        }
    }
    __syncthreads();

    {
        const int n0 = wv * 64;
        f4 acc1[2][4];
#pragma unroll
        for (int rt = 0; rt < 2; ++rt)
#pragma unroll
            for (int c = 0; c < 4; ++c) acc1[rt][c] = (f4){0.f, 0.f, 0.f, 0.f};
        for (int kb = 0; kb < KT1; ++kb) {
            s8 a0 = *(const s8*)&comb[l15 * CS1 + kb * 32 + quad * 8];
            s8 a1 = *(const s8*)&comb[(l15 + 16) * CS1 + kb * 32 + quad * 8];
            s8 bfr[4];
#pragma unroll
            for (int c = 0; c < 4; ++c)
                bfr[c] = *(const s8*)&w1p[((size_t)(kb * H2 + n0 + c * 16 + l15)) * 32 + quad * 8];
#pragma unroll
            for (int c = 0; c < 4; ++c) {
                acc1[0][c] = __builtin_amdgcn_mfma_f32_16x16x32_bf16(a0, bfr[c], acc1[0][c], 0, 0, 0);
                acc1[1][c] = __builtin_amdgcn_mfma_f32_16x16x32_bf16(a1, bfr[c], acc1[1][c], 0, 0, 0);
            }
        }
#pragma unroll
        for (int c = 0; c < 4; ++c) {
            int ccol = n0 + c * 16 + l15;
            float bias = b1g[ccol];
#pragma unroll
            for (int rt = 0; rt < 2; ++rt)
#pragma unroll
                for (int i = 0; i < 4; ++i) {
                    int rr = rt * 16 + quad * 4 + i;
                    hid[rr * HS + ccol] = f2bf(fmaxf(acc1[rt][c][i] + bias, 0.0f));
                }
        }
    }
    __syncthreads();

    {
        const int m0 = wv * 128;
        f4 acc2[2][8];
#pragma unroll
        for (int rt = 0; rt < 2; ++rt)
#pragma unroll
            for (int c = 0; c < 8; ++c) acc2[rt][c] = (f4){0.f, 0.f, 0.f, 0.f};
        for (int kb = 0; kb < KT2; ++kb) {
            s8 a0 = *(const s8*)&hid[l15 * HS + kb * 32 + quad * 8];
            s8 a1 = *(const s8*)&hid[(l15 + 16) * HS + kb * 32 + quad * 8];
            s8 bfr[8];
#pragma unroll
            for (int c = 0; c < 8; ++c)
                bfr[c] = *(const s8*)&w2p[((size_t)(kb * OUTD + m0 + c * 16 + l15)) * 32 + quad * 8];
#pragma unroll
            for (int c = 0; c < 8; ++c) {
                acc2[0][c] = __builtin_amdgcn_mfma_f32_16x16x32_bf16(a0, bfr[c], acc2[0][c], 0, 0, 0);
                acc2[1][c] = __builtin_amdgcn_mfma_f32_16x16x32_bf16(a1, bfr[c], acc2[1][c], 0, 0, 0);
            }
        }
#pragma unroll
        for (int c = 0; c < 8; ++c) {
            int ccol = m0 + c * 16 + l15;
            float bias = b2g[ccol];
#pragma unroll
            for (int rt = 0; rt < 2; ++rt)
#pragma unroll
                for (int i = 0; i < 4; ++i) {
                    int rr = rt * 16 + quad * 4 + i;
                    out[(size_t)(row0 + rr) * OUTD + ccol] = acc2[rt][c][i] + bias;
                }
        }
    }
}

extern "C" void kernel_launch(void* const* d_in, const int* in_sizes, int n_in,
                              void* d_out, int out_size, void* d_ws, size_t ws_size,
                              hipStream_t stream) {
    (void)in_sizes; (void)n_in; (void)out_size; (void)ws_size;
    const float* src_points   = (const float*)d_in[0];
    const float* tgt_points   = (const float*)d_in[1];
    const float* src_features = (const float*)d_in[2];
    const float* w_sem1 = (const float*)d_in[3];
    const float* b_sem1 = (const float*)d_in[4];
    const float* w_sem2 = (const float*)d_in[5];
    const float* b_sem2 = (const float*)d_in[6];
    const float* w_up1  = (const float*)d_in[7];
    const float* b_up1  = (const float*)d_in[8];
    const float* w_up2  = (const float*)d_in[9];
    const float* b_up2  = (const float*)d_in[10];

    float* out    = (float*)d_out;
    float* ups    = out;
    float* logits = out + (size_t)BB * NN * OUTD;

    // workspace layout (3,891,200 B of 4 MiB)
    char* w = (char*)d_ws;
    float4* sp4 = (float4*)w;                          w += (size_t)BB * MM * 16;          // 131072
    float* pd2  = (float*)w;                           w += (size_t)BB * NN * SPLIT * KNN * 4; // 1572864
    float* fw   = (float*)w;                           w += (size_t)BB * NN * KNN * 4;     // 196608
    int*   fidx = (int*)w;                             w += (size_t)BB * NN * KNN * 4;     // 196608
    unsigned short* P    = (unsigned short*)w;         w += (size_t)BB * MM * NC * 2;      // 327680
    unsigned short* pidx = (unsigned short*)w;         w += (size_t)BB * NN * SPLIT * KNN * 2; // 786432
    unsigned short* w1p  = (unsigned short*)w;         w += (size_t)KT1 * H2 * 32 * 2;     // 278528
    unsigned short* w2p  = (unsigned short*)w;         w += (size_t)KT2 * OUTD * 32 * 2;   // 262144
    unsigned short* ws1p = (unsigned short*)w;         w += (size_t)SKT1 * H1 * 32 * 2;    // 131072
    unsigned short* ws2p = (unsigned short*)w;         w += (size_t)SKT2 * 32 * 32 * 2;    // 8192

    prep_kernel<<<dim3((KT1 * H2 * 32 + 255) / 256), dim3(256), 0, stream>>>(
        src_points, w_up1, w_up2, w_sem1, w_sem2, sp4, w1p, w2p, ws1p, ws2p);
    sem_kernel<<<dim3(BB * MM / 32), dim3(256), 0, stream>>>(
        src_features, ws1p, ws2p, b_sem1, b_sem2, logits, P);
    knn_partial<<<dim3(BB * NN / 256, SPLIT), dim3(256), 0, stream>>>(
        sp4, tgt_points, pd2, pidx);
    knn_merge<<<dim3(BB * NN / 256), dim3(256), 0, stream>>>(
        pd2, pidx, tgt_points, fw, fidx);
    up_kernel<<<dim3(BB * NN / RR), dim3(256), 0, stream>>>(
        src_features, P, fidx, fw, w1p, w2p, b_up1, b_up2, ups);
}

// Round 4
// 176.277 us; speedup vs baseline: 2.0502x; 1.1097x over previous
//
#include <hip/hip_runtime.h>
#include <math.h>

#define BB 2
#define MM 4096
#define NN 8192
#define CC 512
#define NC 20
#define OUTD 512
#define H1 128
#define H2 256
#define CIN 532      // C + NC
#define KNN 3
#define SPLIT 8
#define CHUNK (MM / SPLIT)   // 512
#define TG 256       // targets per knn_partial block
#define HALFPTS 256  // points per knn_partial thread

// up_kernel MFMA geometry
#define RR 32        // rows per block
#define CS1 552      // comb row stride in bf16
#define HS 264       // hidden row stride in bf16
#define KT1 17       // k-tiles layer1 (K=544)
#define KT2 8        // k-tiles layer2 (K=256)

// sem_kernel MFMA geometry
#define FS 520       // sfeat stride (bf16), 1040B rows
#define HS2 136      // shid stride (bf16)
#define SKT1 16      // K=512
#define SKT2 4       // K=128

typedef __attribute__((ext_vector_type(8))) short s8;
typedef __attribute__((ext_vector_type(4))) float f4;

__device__ inline unsigned short f2bf(float x) {
    unsigned u = __float_as_uint(x);
    unsigned r = (u + 0x7FFFu + ((u >> 16) & 1u)) >> 16;
    return (unsigned short)r;
}
__device__ inline float bf2f(unsigned short u) {
    return __uint_as_float(((unsigned)u) << 16);
}

// ---------------- Kernel 0: pack sp4 + all bf16 weights ----------------
__global__ __launch_bounds__(256) void prep_kernel(
    const float* __restrict__ srcp,
    const float* __restrict__ wu1, const float* __restrict__ wu2,
    const float* __restrict__ ws1, const float* __restrict__ ws2,
    float4* __restrict__ sp4,
    unsigned short* __restrict__ w1p, unsigned short* __restrict__ w2p,
    unsigned short* __restrict__ ws1p, unsigned short* __restrict__ ws2p)
{
    int i = blockIdx.x * 256 + threadIdx.x;
    if (i < BB * MM) {      // 8192 source points -> (x,y,z,|s|^2)
        float x = srcp[(size_t)i * 3 + 0];
        float y = srcp[(size_t)i * 3 + 1];
        float z = srcp[(size_t)i * 3 + 2];
        sp4[i] = make_float4(x, y, z, x * x + y * y + z * z);
    }
    if (i < KT1 * H2 * 32) {            // 139264: upsample L1
        int kk = i & 31, n = (i >> 5) & 255, kb = i >> 13;
        int k = kb * 32 + kk;
        w1p[i] = f2bf((k < CIN) ? wu1[(size_t)k * H2 + n] : 0.0f);
    }
    if (i < KT2 * OUTD * 32) {          // 131072: upsample L2
        int kk = i & 31, n = (i >> 5) & 511, kb = i >> 14;
        int k = kb * 32 + kk;
        w2p[i] = f2bf(wu2[(size_t)k * OUTD + n]);
    }
    if (i < SKT1 * H1 * 32) {           // 65536: semantic L1
        int kk = i & 31, n = (i >> 5) & 127, kb = i >> 12;
        int k = kb * 32 + kk;
        ws1p[i] = f2bf(ws1[(size_t)k * H1 + n]);
    }
    if (i < SKT2 * 32 * 32) {           // 4096: semantic L2 (N padded 20->32)
        int kk = i & 31, n = (i >> 5) & 31, kb = i >> 10;
        int k = kb * 32 + kk;
        ws2p[i] = f2bf((n < NC) ? ws2[(size_t)k * NC + n] : 0.0f);
    }
}

// ---------------- Kernel A: semantic MLP (bf16 MFMA) + softmax probs ----------------
__global__ __launch_bounds__(256) void sem_kernel(
    const float* __restrict__ feat,
    const unsigned short* __restrict__ ws1p, const unsigned short* __restrict__ ws2p,
    const float* __restrict__ b1g, const float* __restrict__ b2g,
    float* __restrict__ logits_out, unsigned short* __restrict__ P)
{
    __shared__ unsigned short sfeat[32 * FS];
    __shared__ unsigned short shid[32 * HS2];
    __shared__ float slg[32][33];
    const int tid = threadIdx.x;
    const int row0 = blockIdx.x * 32;
    const int lane = tid & 63;
    const int wv = tid >> 6;
    const int l15 = lane & 15;
    const int quad = lane >> 4;

    {
        const int r = tid >> 3, p = tid & 7;
        const float4* fr = (const float4*)(feat + (size_t)(row0 + r) * CC);
#pragma unroll 4
        for (int j = 0; j < 16; ++j) {
            int c4 = j * 8 + p;
            float4 a = fr[c4];
            ushort4 s;
            s.x = f2bf(a.x); s.y = f2bf(a.y); s.z = f2bf(a.z); s.w = f2bf(a.w);
            *(ushort4*)&sfeat[r * FS + c4 * 4] = s;
        }
    }
    __syncthreads();

    {
        const int n0 = wv * 32;
        f4 acc[2][2];
#pragma unroll
        for (int rt = 0; rt < 2; ++rt)
#pragma unroll
            for (int c = 0; c < 2; ++c) acc[rt][c] = (f4){0.f, 0.f, 0.f, 0.f};
        for (int kb = 0; kb < SKT1; ++kb) {
            s8 a0 = *(const s8*)&sfeat[l15 * FS + kb * 32 + quad * 8];
            s8 a1 = *(const s8*)&sfeat[(l15 + 16) * FS + kb * 32 + quad * 8];
#pragma unroll
            for (int c = 0; c < 2; ++c) {
                s8 bf = *(const s8*)&ws1p[((size_t)(kb * H1 + n0 + c * 16 + l15)) * 32 + quad * 8];
                acc[0][c] = __builtin_amdgcn_mfma_f32_16x16x32_bf16(a0, bf, acc[0][c], 0, 0, 0);
                acc[1][c] = __builtin_amdgcn_mfma_f32_16x16x32_bf16(a1, bf, acc[1][c], 0, 0, 0);
            }
        }
#pragma unroll
        for (int c = 0; c < 2; ++c) {
            int col = n0 + c * 16 + l15;
            float bias = b1g[col];
#pragma unroll
            for (int rt = 0; rt < 2; ++rt)
#pragma unroll
                for (int i = 0; i < 4; ++i) {
                    int rr = rt * 16 + quad * 4 + i;
                    shid[rr * HS2 + col] = f2bf(fmaxf(acc[rt][c][i] + bias, 0.0f));
                }
        }
    }
    __syncthreads();

    {
        const int rt = wv & 1, ct = wv >> 1;
        f4 acc2 = (f4){0.f, 0.f, 0.f, 0.f};
        for (int kb = 0; kb < SKT2; ++kb) {
            s8 a = *(const s8*)&shid[(rt * 16 + l15) * HS2 + kb * 32 + quad * 8];
            s8 bf = *(const s8*)&ws2p[((size_t)(kb * 32 + ct * 16 + l15)) * 32 + quad * 8];
            acc2 = __builtin_amdgcn_mfma_f32_16x16x32_bf16(a, bf, acc2, 0, 0, 0);
        }
        int col = ct * 16 + l15;
        float bias = (col < NC) ? b2g[col] : 0.0f;
#pragma unroll
        for (int i = 0; i < 4; ++i) {
            int rr = rt * 16 + quad * 4 + i;
            float v = acc2[i] + bias;
            slg[rr][col] = v;
            if (col < NC)
                logits_out[(size_t)(row0 + rr) * NC + col] = v;
        }
    }
    __syncthreads();

    if (tid < 32) {
        int r = tid;
        float mx = -1e30f;
        for (int nc = 0; nc < NC; ++nc) mx = fmaxf(mx, slg[r][nc]);
        float s = 0.0f;
        float e[NC];
#pragma unroll
        for (int nc = 0; nc < NC; ++nc) { e[nc] = __expf(slg[r][nc] - mx); s += e[nc]; }
        float inv = 1.0f / s;
#pragma unroll
        for (int nc = 0; nc < NC; ++nc)
            P[(size_t)(row0 + r) * NC + nc] = f2bf(e[nc] * inv);
    }
}

// ---------------- Kernel B: partial kNN — scalar-load batches + LDS half-merge ----------------
// grid: (B*N/TG, SPLIT) x 512 threads. Thread half h scans points
// [chunk*512 + h*256, +256); halves merge via LDS.
__global__ __launch_bounds__(512) void knn_partial(
    const float4* __restrict__ sp4, const float* __restrict__ tgtp,
    float* __restrict__ pd2, unsigned short* __restrict__ pidx)
{
    __shared__ float ld[TG * KNN];
    __shared__ int   li[TG * KNN];
    const int tid = threadIdx.x;
    const int lt = tid & (TG - 1);
    const int half = tid >> 8;
    const int t = blockIdx.x * TG + lt;
    const int bu = blockIdx.x >> 5;            // PROVABLY uniform batch (32 groups/batch)
    const int chunk = blockIdx.y;
    const int mbase = chunk * CHUNK + half * HALFPTS;
    const float4* sp = sp4 + (size_t)bu * MM + mbase;   // scalar pointer -> s_load

    const float tx = tgtp[(size_t)t * 3 + 0];
    const float ty = tgtp[(size_t)t * 3 + 1];
    const float tz = tgtp[(size_t)t * 3 + 2];
    const float m2x = -2.0f * tx, m2y = -2.0f * ty, m2z = -2.0f * tz;

    // dual independent chains (even/odd) for ILP
    float a0 = 1e30f, a1 = 1e30f, a2 = 1e30f;
    int ia0 = 0, ia1 = 0, ia2 = 0;
    float c0 = 1e30f, c1 = 1e30f, c2 = 1e30f;
    int ic0 = 0, ic1 = 0, ic2 = 0;

    for (int mb = 0; mb < HALFPTS; mb += 16) {
        float4 pp[16];
#pragma unroll
        for (int j = 0; j < 16; ++j) pp[j] = sp[mb + j];   // batched s_loads
#pragma unroll
        for (int j = 0; j < 16; j += 2) {
            float4 p = pp[j], q = pp[j + 1];
            float da = fmaf(m2x, p.x, fmaf(m2y, p.y, fmaf(m2z, p.z, p.w)));
            float dc = fmaf(m2x, q.x, fmaf(m2y, q.y, fmaf(m2z, q.z, q.w)));
            const int ma = mbase + mb + j;
            const int mc = ma + 1;
            {
                bool l2 = da < a2, l1 = da < a1, l0 = da < a0;
                a2 = l1 ? a1 : (l2 ? da : a2); ia2 = l1 ? ia1 : (l2 ? ma : ia2);
                a1 = l0 ? a0 : (l1 ? da : a1); ia1 = l0 ? ia0 : (l1 ? ma : ia1);
                a0 = l0 ? da : a0;             ia0 = l0 ? ma : ia0;
            }
            {
                bool l2 = dc < c2, l1 = dc < c1, l0 = dc < c0;
                c2 = l1 ? c1 : (l2 ? dc : c2); ic2 = l1 ? ic1 : (l2 ? mc : ic2);
                c1 = l0 ? c0 : (l1 ? dc : c1); ic1 = l0 ? ic0 : (l1 ? mc : ic1);
                c0 = l0 ? dc : c0;             ic0 = l0 ? mc : ic0;
            }
        }
    }
    // merge chain C into chain A with index tie-break (stable top-k semantics)
#pragma unroll
    for (int j = 0; j < 3; ++j) {
        float d = (j == 0) ? c0 : (j == 1) ? c1 : c2;
        int   i = (j == 0) ? ic0 : (j == 1) ? ic1 : ic2;
        bool e2 = (d < a2) || (d == a2 && i < ia2);
        bool e1 = (d < a1) || (d == a1 && i < ia1);
        bool e0 = (d < a0) || (d == a0 && i < ia0);
        a2 = e1 ? a1 : (e2 ? d : a2); ia2 = e1 ? ia1 : (e2 ? i : ia2);
        a1 = e0 ? a0 : (e1 ? d : a1); ia1 = e0 ? ia0 : (e1 ? i : ia1);
        a0 = e0 ? d : a0;             ia0 = e0 ? i : ia0;
    }

    if (half) {
        ld[lt * 3 + 0] = a0; ld[lt * 3 + 1] = a1; ld[lt * 3 + 2] = a2;
        li[lt * 3 + 0] = ia0; li[lt * 3 + 1] = ia1; li[lt * 3 + 2] = ia2;
    }
    __syncthreads();
    if (!half) {
#pragma unroll
        for (int j = 0; j < 3; ++j) {
            float d = ld[lt * 3 + j];
            int   i = li[lt * 3 + j];
            bool e2 = (d < a2) || (d == a2 && i < ia2);
            bool e1 = (d < a1) || (d == a1 && i < ia1);
            bool e0 = (d < a0) || (d == a0 && i < ia0);
            a2 = e1 ? a1 : (e2 ? d : a2); ia2 = e1 ? ia1 : (e2 ? i : ia2);
            a1 = e0 ? a0 : (e1 ? d : a1); ia1 = e0 ? ia0 : (e1 ? i : ia1);
            a0 = e0 ? d : a0;             ia0 = e0 ? i : ia0;
        }
        size_t o = ((size_t)t * SPLIT + chunk) * KNN;
        pd2[o + 0] = a0; pd2[o + 1] = a1; pd2[o + 2] = a2;
        pidx[o + 0] = (unsigned short)ia0;
        pidx[o + 1] = (unsigned short)ia1;
        pidx[o + 2] = (unsigned short)ia2;
    }
}

// ---------------- Kernel C: merge partials, softmax(-d) weights ----------------
__global__ __launch_bounds__(256) void knn_merge(
    const float* __restrict__ pd2, const unsigned short* __restrict__ pidx,
    const float* __restrict__ tgtp,
    float* __restrict__ fw, int* __restrict__ fidx)
{
    const int t = blockIdx.x * 256 + threadIdx.x;
    float b0 = 1e30f, b1 = 1e30f, b2 = 1e30f;
    int i0 = 0, i1 = 0, i2 = 0;
    size_t base = (size_t)t * SPLIT * KNN;
#pragma unroll
    for (int j = 0; j < SPLIT * KNN; ++j) {
        float d2 = pd2[base + j];
        int m = pidx[base + j];
        bool l2 = d2 < b2, l1 = d2 < b1, l0 = d2 < b0;
        b2 = l1 ? b1 : (l2 ? d2 : b2);
        i2 = l1 ? i1 : (l2 ? m : i2);
        b1 = l0 ? b0 : (l1 ? d2 : b1);
        i1 = l0 ? i0 : (l1 ? m : i1);
        b0 = l0 ? d2 : b0;
        i0 = l0 ? m : i0;
    }
    const float tx = tgtp[(size_t)t * 3 + 0];
    const float ty = tgtp[(size_t)t * 3 + 1];
    const float tz = tgtp[(size_t)t * 3 + 2];
    const float t2 = tx * tx + ty * ty + tz * tz;
    float d0 = sqrtf(fmaxf(b0 + t2, 0.0f));
    float d1 = sqrtf(fmaxf(b1 + t2, 0.0f));
    float d2s = sqrtf(fmaxf(b2 + t2, 0.0f));
    float e0 = 1.0f;
    float e1 = __expf(d0 - d1);
    float e2 = __expf(d0 - d2s);
    float inv = 1.0f / (e0 + e1 + e2);
    size_t o = (size_t)t * KNN;
    fw[o + 0] = e0 * inv; fw[o + 1] = e1 * inv; fw[o + 2] = e2 * inv;
    fidx[o + 0] = i0; fidx[o + 1] = i1; fidx[o + 2] = i2;
}

// ---------------- Kernel D: gather + fuse + bf16-MFMA 2-layer MLP ----------------
__global__ __launch_bounds__(256) void up_kernel(
    const float* __restrict__ feat, const unsigned short* __restrict__ P,
    const int* __restrict__ fidx, const float* __restrict__ fw,
    const unsigned short* __restrict__ w1p, const unsigned short* __restrict__ w2p,
    const float* __restrict__ b1g, const float* __restrict__ b2g,
    float* __restrict__ out)
{
    __shared__ unsigned short comb[RR * CS1];
    __shared__ unsigned short hid[RR * HS];
    const int tid = threadIdx.x;
    const int row0 = blockIdx.x * RR;
    const int lane = tid & 63;
    const int wv = tid >> 6;
    const int l15 = lane & 15;
    const int quad = lane >> 4;

    {
        const int r = tid >> 3, p = tid & 7;
        int row = row0 + r;
        int b = row >> 13;
        size_t o = (size_t)row * KNN;
        int j0 = fidx[o], j1 = fidx[o + 1], j2 = fidx[o + 2];
        float g0 = fw[o], g1 = fw[o + 1], g2 = fw[o + 2];
        const float* F = feat + (size_t)b * MM * CC;
        const float4* f0 = (const float4*)(F + (size_t)j0 * CC);
        const float4* f1 = (const float4*)(F + (size_t)j1 * CC);
        const float4* f2 = (const float4*)(F + (size_t)j2 * CC);
#pragma unroll 4
        for (int j = 0; j < 16; ++j) {
            int c4 = j * 8 + p;
            float4 a0 = f0[c4], a1 = f1[c4], a2 = f2[c4];
            ushort4 s;
            s.x = f2bf(g0 * a0.x + g1 * a1.x + g2 * a2.x);
            s.y = f2bf(g0 * a0.y + g1 * a1.y + g2 * a2.y);
            s.z = f2bf(g0 * a0.z + g1 * a1.z + g2 * a2.z);
            s.w = f2bf(g0 * a0.w + g1 * a1.w + g2 * a2.w);
            *(ushort4*)&comb[r * CS1 + c4 * 4] = s;
        }
        const unsigned short* Pb = P + (size_t)b * MM * NC;
        if (p < 4) {
            for (int q = p; q < 32; q += 4) {
                unsigned short v = 0;
                if (q < NC)
                    v = f2bf((bf2f(Pb[(size_t)j0 * NC + q]) + bf2f(Pb[(size_t)j1 * NC + q]) +
                              bf2f(Pb[(size_t)j2 * NC + q])) * (1.0f / 3.0f));
                comb[r * CS1 + 512 + q] = v;
            }
        }
    }
    __syncthreads();

    {
        const int n0 = wv * 64;
        f4 acc1[2][4];
#pragma unroll
        for (int rt = 0; rt < 2; ++rt)
#pragma unroll
            for (int c = 0; c < 4; ++c) acc1[rt][c] = (f4){0.f, 0.f, 0.f, 0.f};
        for (int kb = 0; kb < KT1; ++kb) {
            s8 a0 = *(const s8*)&comb[l15 * CS1 + kb * 32 + quad * 8];
            s8 a1 = *(const s8*)&comb[(l15 + 16) * CS1 + kb * 32 + quad * 8];
            s8 bfr[4];
#pragma unroll
            for (int c = 0; c < 4; ++c)
                bfr[c] = *(const s8*)&w1p[((size_t)(kb * H2 + n0 + c * 16 + l15)) * 32 + quad * 8];
#pragma unroll
            for (int c = 0; c < 4; ++c) {
                acc1[0][c] = __builtin_amdgcn_mfma_f32_16x16x32_bf16(a0, bfr[c], acc1[0][c], 0, 0, 0);
                acc1[1][c] = __builtin_amdgcn_mfma_f32_16x16x32_bf16(a1, bfr[c], acc1[1][c], 0, 0, 0);
            }
        }
#pragma unroll
        for (int c = 0; c < 4; ++c) {
            int ccol = n0 + c * 16 + l15;
            float bias = b1g[ccol];
#pragma unroll
            for (int rt = 0; rt < 2; ++rt)
#pragma unroll
                for (int i = 0; i < 4; ++i) {
                    int rr = rt * 16 + quad * 4 + i;
                    hid[rr * HS + ccol] = f2bf(fmaxf(acc1[rt][c][i] + bias, 0.0f));
                }
        }
    }
    __syncthreads();

    {
        const int m0 = wv * 128;
        f4 acc2[2][8];
#pragma unroll
        for (int rt = 0; rt < 2; ++rt)
#pragma unroll
            for (int c = 0; c < 8; ++c) acc2[rt][c] = (f4){0.f, 0.f, 0.f, 0.f};
        for (int kb = 0; kb < KT2; ++kb) {
            s8 a0 = *(const s8*)&hid[l15 * HS + kb * 32 + quad * 8];
            s8 a1 = *(const s8*)&hid[(l15 + 16) * HS + kb * 32 + quad * 8];
            s8 bfr[8];
#pragma unroll
            for (int c = 0; c < 8; ++c)
                bfr[c] = *(const s8*)&w2p[((size_t)(kb * OUTD + m0 + c * 16 + l15)) * 32 + quad * 8];
#pragma unroll
            for (int c = 0; c < 8; ++c) {
                acc2[0][c] = __builtin_amdgcn_mfma_f32_16x16x32_bf16(a0, bfr[c], acc2[0][c], 0, 0, 0);
                acc2[1][c] = __builtin_amdgcn_mfma_f32_16x16x32_bf16(a1, bfr[c], acc2[1][c], 0, 0, 0);
            }
        }
#pragma unroll
        for (int c = 0; c < 8; ++c) {
            int ccol = m0 + c * 16 + l15;
            float bias = b2g[ccol];
#pragma unroll
            for (int rt = 0; rt < 2; ++rt)
#pragma unroll
                for (int i = 0; i < 4; ++i) {
                    int rr = rt * 16 + quad * 4 + i;
                    out[(size_t)(row0 + rr) * OUTD + ccol] = acc2[rt][c][i] + bias;
                }
        }
    }
}

extern "C" void kernel_launch(void* const* d_in, const int* in_sizes, int n_in,
                              void* d_out, int out_size, void* d_ws, size_t ws_size,
                              hipStream_t stream) {
    (void)in_sizes; (void)n_in; (void)out_size; (void)ws_size;
    const float* src_points   = (const float*)d_in[0];
    const float* tgt_points   = (const float*)d_in[1];
    const float* src_features = (const float*)d_in[2];
    const float* w_sem1 = (const float*)d_in[3];
    const float* b_sem1 = (const float*)d_in[4];
    const float* w_sem2 = (const float*)d_in[5];
    const float* b_sem2 = (const float*)d_in[6];
    const float* w_up1  = (const float*)d_in[7];
    const float* b_up1  = (const float*)d_in[8];
    const float* w_up2  = (const float*)d_in[9];
    const float* b_up2  = (const float*)d_in[10];

    float* out    = (float*)d_out;
    float* ups    = out;
    float* logits = out + (size_t)BB * NN * OUTD;

    // workspace layout (3,891,200 B of 4 MiB)
    char* w = (char*)d_ws;
    float4* sp4 = (float4*)w;                          w += (size_t)BB * MM * 16;          // 131072
    float* pd2  = (float*)w;                           w += (size_t)BB * NN * SPLIT * KNN * 4; // 1572864
    float* fw   = (float*)w;                           w += (size_t)BB * NN * KNN * 4;     // 196608
    int*   fidx = (int*)w;                             w += (size_t)BB * NN * KNN * 4;     // 196608
    unsigned short* P    = (unsigned short*)w;         w += (size_t)BB * MM * NC * 2;      // 327680
    unsigned short* pidx = (unsigned short*)w;         w += (size_t)BB * NN * SPLIT * KNN * 2; // 786432
    unsigned short* w1p  = (unsigned short*)w;         w += (size_t)KT1 * H2 * 32 * 2;     // 278528
    unsigned short* w2p  = (unsigned short*)w;         w += (size_t)KT2 * OUTD * 32 * 2;   // 262144
    unsigned short* ws1p = (unsigned short*)w;         w += (size_t)SKT1 * H1 * 32 * 2;    // 131072
    unsigned short* ws2p = (unsigned short*)w;         w += (size_t)SKT2 * 32 * 32 * 2;    // 8192

    prep_kernel<<<dim3((KT1 * H2 * 32 + 255) / 256), dim3(256), 0, stream>>>(
        src_points, w_up1, w_up2, w_sem1, w_sem2, sp4, w1p, w2p, ws1p, ws2p);
    sem_kernel<<<dim3(BB * MM / 32), dim3(256), 0, stream>>>(
        src_features, ws1p, ws2p, b_sem1, b_sem2, logits, P);
    knn_partial<<<dim3(BB * NN / TG, SPLIT), dim3(512), 0, stream>>>(
        sp4, tgt_points, pd2, pidx);
    knn_merge<<<dim3(BB * NN / 256), dim3(256), 0, stream>>>(
        pd2, pidx, tgt_points, fw, fidx);
    up_kernel<<<dim3(BB * NN / RR), dim3(256), 0, stream>>>(
        src_features, P, fidx, fw, w1p, w2p, b_up1, b_up2, ups);
}

// Round 5
// 168.297 us; speedup vs baseline: 2.1474x; 1.0474x over previous
//
#include <hip/hip_runtime.h>
#include <math.h>

#define BB 2
#define MM 4096
#define NN 8192
#define CC 512
#define NC 20
#define OUTD 512
#define H1 128
#define H2 256
#define CIN 532      // C + NC
#define KNN 3
#define SPLIT 8
#define CHUNK (MM / SPLIT)   // 512
#define QTR (CHUNK / 4)      // 128 points per chain

// up_kernel MFMA geometry
#define RR 32        // rows per block
#define CS1 552      // comb row stride in bf16
#define HS 264       // hidden row stride in bf16
#define KT1 17       // k-tiles layer1 (K=544)
#define KT2 8        // k-tiles layer2 (K=256)

// sem_kernel MFMA geometry
#define FS 520       // sfeat stride (bf16)
#define HS2 136      // shid stride (bf16)
#define SKT1 16      // K=512
#define SKT2 4       // K=128

typedef __attribute__((ext_vector_type(8))) short s8;
typedef __attribute__((ext_vector_type(4))) float f4;

__device__ inline unsigned short f2bf(float x) {
    unsigned u = __float_as_uint(x);
    unsigned r = (u + 0x7FFFu + ((u >> 16) & 1u)) >> 16;
    return (unsigned short)r;
}
__device__ inline float bf2f(unsigned short u) {
    return __uint_as_float(((unsigned)u) << 16);
}

// ---------------- Kernel 0: pack sp4 + all bf16 weights ----------------
__global__ __launch_bounds__(256) void prep_kernel(
    const float* __restrict__ srcp,
    const float* __restrict__ wu1, const float* __restrict__ wu2,
    const float* __restrict__ ws1, const float* __restrict__ ws2,
    float4* __restrict__ sp4,
    unsigned short* __restrict__ w1p, unsigned short* __restrict__ w2p,
    unsigned short* __restrict__ ws1p, unsigned short* __restrict__ ws2p)
{
    int i = blockIdx.x * 256 + threadIdx.x;
    if (i < BB * MM) {      // 8192 source points -> (x,y,z,|s|^2)
        float x = srcp[(size_t)i * 3 + 0];
        float y = srcp[(size_t)i * 3 + 1];
        float z = srcp[(size_t)i * 3 + 2];
        sp4[i] = make_float4(x, y, z, x * x + y * y + z * z);
    }
    if (i < KT1 * H2 * 32) {            // upsample L1
        int kk = i & 31, n = (i >> 5) & 255, kb = i >> 13;
        int k = kb * 32 + kk;
        w1p[i] = f2bf((k < CIN) ? wu1[(size_t)k * H2 + n] : 0.0f);
    }
    if (i < KT2 * OUTD * 32) {          // upsample L2
        int kk = i & 31, n = (i >> 5) & 511, kb = i >> 14;
        int k = kb * 32 + kk;
        w2p[i] = f2bf(wu2[(size_t)k * OUTD + n]);
    }
    if (i < SKT1 * H1 * 32) {           // semantic L1
        int kk = i & 31, n = (i >> 5) & 127, kb = i >> 12;
        int k = kb * 32 + kk;
        ws1p[i] = f2bf(ws1[(size_t)k * H1 + n]);
    }
    if (i < SKT2 * 32 * 32) {           // semantic L2 (N padded 20->32)
        int kk = i & 31, n = (i >> 5) & 31, kb = i >> 10;
        int k = kb * 32 + kk;
        ws2p[i] = f2bf((n < NC) ? ws2[(size_t)k * NC + n] : 0.0f);
    }
}

// ---------------- Kernel A: semantic MLP (bf16 MFMA) + softmax probs ----------------
__global__ __launch_bounds__(256) void sem_kernel(
    const float* __restrict__ feat,
    const unsigned short* __restrict__ ws1p, const unsigned short* __restrict__ ws2p,
    const float* __restrict__ b1g, const float* __restrict__ b2g,
    float* __restrict__ logits_out, unsigned short* __restrict__ P)
{
    __shared__ unsigned short sfeat[32 * FS];
    __shared__ unsigned short shid[32 * HS2];
    __shared__ float slg[32][33];
    const int tid = threadIdx.x;
    const int row0 = blockIdx.x * 32;
    const int lane = tid & 63;
    const int wv = tid >> 6;
    const int l15 = lane & 15;
    const int quad = lane >> 4;

    {
        const int r = tid >> 3, p = tid & 7;
        const float4* fr = (const float4*)(feat + (size_t)(row0 + r) * CC);
#pragma unroll 4
        for (int j = 0; j < 16; ++j) {
            int c4 = j * 8 + p;
            float4 a = fr[c4];
            ushort4 s;
            s.x = f2bf(a.x); s.y = f2bf(a.y); s.z = f2bf(a.z); s.w = f2bf(a.w);
            *(ushort4*)&sfeat[r * FS + c4 * 4] = s;
        }
    }
    __syncthreads();

    {
        const int n0 = wv * 32;
        f4 acc[2][2];
#pragma unroll
        for (int rt = 0; rt < 2; ++rt)
#pragma unroll
            for (int c = 0; c < 2; ++c) acc[rt][c] = (f4){0.f, 0.f, 0.f, 0.f};
        for (int kb = 0; kb < SKT1; ++kb) {
            s8 a0 = *(const s8*)&sfeat[l15 * FS + kb * 32 + quad * 8];
            s8 a1 = *(const s8*)&sfeat[(l15 + 16) * FS + kb * 32 + quad * 8];
#pragma unroll
            for (int c = 0; c < 2; ++c) {
                s8 bf = *(const s8*)&ws1p[((size_t)(kb * H1 + n0 + c * 16 + l15)) * 32 + quad * 8];
                acc[0][c] = __builtin_amdgcn_mfma_f32_16x16x32_bf16(a0, bf, acc[0][c], 0, 0, 0);
                acc[1][c] = __builtin_amdgcn_mfma_f32_16x16x32_bf16(a1, bf, acc[1][c], 0, 0, 0);
            }
        }
#pragma unroll
        for (int c = 0; c < 2; ++c) {
            int col = n0 + c * 16 + l15;
            float bias = b1g[col];
#pragma unroll
            for (int rt = 0; rt < 2; ++rt)
#pragma unroll
                for (int i = 0; i < 4; ++i) {
                    int rr = rt * 16 + quad * 4 + i;
                    shid[rr * HS2 + col] = f2bf(fmaxf(acc[rt][c][i] + bias, 0.0f));
                }
        }
    }
    __syncthreads();

    {
        const int rt = wv & 1, ct = wv >> 1;
        f4 acc2 = (f4){0.f, 0.f, 0.f, 0.f};
        for (int kb = 0; kb < SKT2; ++kb) {
            s8 a = *(const s8*)&shid[(rt * 16 + l15) * HS2 + kb * 32 + quad * 8];
            s8 bf = *(const s8*)&ws2p[((size_t)(kb * 32 + ct * 16 + l15)) * 32 + quad * 8];
            acc2 = __builtin_amdgcn_mfma_f32_16x16x32_bf16(a, bf, acc2, 0, 0, 0);
        }
        int col = ct * 16 + l15;
        float bias = (col < NC) ? b2g[col] : 0.0f;
#pragma unroll
        for (int i = 0; i < 4; ++i) {
            int rr = rt * 16 + quad * 4 + i;
            float v = acc2[i] + bias;
            slg[rr][col] = v;
            if (col < NC)
                logits_out[(size_t)(row0 + rr) * NC + col] = v;
        }
    }
    __syncthreads();

    if (tid < 32) {
        int r = tid;
        float mx = -1e30f;
        for (int nc = 0; nc < NC; ++nc) mx = fmaxf(mx, slg[r][nc]);
        float s = 0.0f;
        float e[NC];
#pragma unroll
        for (int nc = 0; nc < NC; ++nc) { e[nc] = __expf(slg[r][nc] - mx); s += e[nc]; }
        float inv = 1.0f / s;
#pragma unroll
        for (int nc = 0; nc < NC; ++nc)
            P[(size_t)(row0 + r) * NC + nc] = f2bf(e[nc] * inv);
    }
}

// ---------------- Kernel B: partial kNN — LDS broadcast + 4 insert chains ----------------
// grid: (B*N/256, SPLIT) x 256 threads. Chunk staged in LDS; every thread scans
// all 512 points via broadcast ds_read (conflict-free). 4 chains over disjoint
// ascending quarters give ILP; plain '<' at merge keeps stable-tie semantics.
__global__ __launch_bounds__(256) void knn_partial(
    const float4* __restrict__ sp4, const float* __restrict__ tgtp,
    float* __restrict__ pd2, unsigned short* __restrict__ pidx)
{
    __shared__ float4 pts[CHUNK];   // 8 KB
    const int tid = threadIdx.x;
    const int t = blockIdx.x * 256 + tid;
    const int bu = blockIdx.x >> 5;           // 32 blocks.x per batch -> uniform
    const int chunk = blockIdx.y;
    const int mbase = chunk * CHUNK;
    const float4* sp = sp4 + (size_t)bu * MM + mbase;
    for (int i = tid; i < CHUNK; i += 256) pts[i] = sp[i];
    __syncthreads();

    const float tx = tgtp[(size_t)t * 3 + 0];
    const float ty = tgtp[(size_t)t * 3 + 1];
    const float tz = tgtp[(size_t)t * 3 + 2];
    const float m2x = -2.0f * tx, m2y = -2.0f * ty, m2z = -2.0f * tz;

    float b0[4], b1[4], b2[4];
    int i0[4], i1[4], i2[4];
#pragma unroll
    for (int k = 0; k < 4; ++k) {
        b0[k] = b1[k] = b2[k] = 1e30f;
        i0[k] = i1[k] = i2[k] = 0;
    }

#pragma unroll 2
    for (int m = 0; m < QTR; ++m) {
#pragma unroll
        for (int k = 0; k < 4; ++k) {
            float4 p = pts[k * QTR + m];          // broadcast read
            float d = fmaf(m2x, p.x, fmaf(m2y, p.y, fmaf(m2z, p.z, p.w)));
            int mi = mbase + k * QTR + m;          // wave-uniform -> SGPR
            bool l2 = d < b2[k], l1 = d < b1[k], l0 = d < b0[k];
            b2[k] = l1 ? b1[k] : (l2 ? d : b2[k]); i2[k] = l1 ? i1[k] : (l2 ? mi : i2[k]);
            b1[k] = l0 ? b0[k] : (l1 ? d : b1[k]); i1[k] = l0 ? i0[k] : (l1 ? mi : i1[k]);
            b0[k] = l0 ? d : b0[k];                i0[k] = l0 ? mi : i0[k];
        }
    }
    // merge chains 1..3 into chain 0 (later chains have strictly larger indices,
    // so plain '<' keeps the earlier-index incumbent on exact ties)
#pragma unroll
    for (int k = 1; k < 4; ++k) {
#pragma unroll
        for (int j = 0; j < 3; ++j) {
            float d = (j == 0) ? b0[k] : (j == 1) ? b1[k] : b2[k];
            int   i = (j == 0) ? i0[k] : (j == 1) ? i1[k] : i2[k];
            bool e2 = d < b2[0], e1 = d < b1[0], e0 = d < b0[0];
            b2[0] = e1 ? b1[0] : (e2 ? d : b2[0]); i2[0] = e1 ? i1[0] : (e2 ? i : i2[0]);
            b1[0] = e0 ? b0[0] : (e1 ? d : b1[0]); i1[0] = e0 ? i0[0] : (e1 ? i : i1[0]);
            b0[0] = e0 ? d : b0[0];                i0[0] = e0 ? i : i0[0];
        }
    }
    size_t o = ((size_t)t * SPLIT + chunk) * KNN;
    pd2[o + 0] = b0[0]; pd2[o + 1] = b1[0]; pd2[o + 2] = b2[0];
    pidx[o + 0] = (unsigned short)i0[0];
    pidx[o + 1] = (unsigned short)i1[0];
    pidx[o + 2] = (unsigned short)i2[0];
}

// ---------------- Kernel D: merge partials + gather + bf16-MFMA 2-layer MLP ----------------
__global__ __launch_bounds__(256) void up_kernel(
    const float* __restrict__ feat, const unsigned short* __restrict__ P,
    const float* __restrict__ pd2, const unsigned short* __restrict__ pidx,
    const float* __restrict__ tgtp,
    const unsigned short* __restrict__ w1p, const unsigned short* __restrict__ w2p,
    const float* __restrict__ b1g, const float* __restrict__ b2g,
    float* __restrict__ out)
{
    __shared__ unsigned short comb[RR * CS1];
    __shared__ unsigned short hid[RR * HS];
    __shared__ float sg[RR][3];
    __shared__ int   sj[RR][3];
    const int tid = threadIdx.x;
    const int row0 = blockIdx.x * RR;
    const int lane = tid & 63;
    const int wv = tid >> 6;
    const int l15 = lane & 15;
    const int quad = lane >> 4;

    // ---- stage A: per-row merge of SPLIT partial top-3 + softmax(-d) weights ----
    if (tid < RR) {
        int row = row0 + tid;
        float b0 = 1e30f, b1 = 1e30f, b2 = 1e30f;
        int i0 = 0, i1 = 0, i2 = 0;
        size_t base = (size_t)row * SPLIT * KNN;
#pragma unroll
        for (int j = 0; j < SPLIT * KNN; ++j) {
            float d = pd2[base + j];
            int m = pidx[base + j];
            bool l2 = d < b2, l1 = d < b1, l0 = d < b0;
            b2 = l1 ? b1 : (l2 ? d : b2); i2 = l1 ? i1 : (l2 ? m : i2);
            b1 = l0 ? b0 : (l1 ? d : b1); i1 = l0 ? i0 : (l1 ? m : i1);
            b0 = l0 ? d : b0;             i0 = l0 ? m : i0;
        }
        float tx = tgtp[(size_t)row * 3 + 0];
        float ty = tgtp[(size_t)row * 3 + 1];
        float tz = tgtp[(size_t)row * 3 + 2];
        float t2 = tx * tx + ty * ty + tz * tz;
        float d0 = sqrtf(fmaxf(b0 + t2, 0.0f));
        float d1 = sqrtf(fmaxf(b1 + t2, 0.0f));
        float d2v = sqrtf(fmaxf(b2 + t2, 0.0f));
        float e1 = __expf(d0 - d1);
        float e2 = __expf(d0 - d2v);
        float inv = 1.0f / (1.0f + e1 + e2);
        sg[tid][0] = inv; sg[tid][1] = e1 * inv; sg[tid][2] = e2 * inv;
        sj[tid][0] = i0; sj[tid][1] = i1; sj[tid][2] = i2;
    }
    __syncthreads();

    // ---- gather + fuse ----
    {
        const int r = tid >> 3, p = tid & 7;
        int row = row0 + r;
        int b = row >> 13;
        int j0 = sj[r][0], j1 = sj[r][1], j2 = sj[r][2];
        float g0 = sg[r][0], g1 = sg[r][1], g2 = sg[r][2];
        const float* F = feat + (size_t)b * MM * CC;
        const float4* f0 = (const float4*)(F + (size_t)j0 * CC);
        const float4* f1 = (const float4*)(F + (size_t)j1 * CC);
        const float4* f2 = (const float4*)(F + (size_t)j2 * CC);
#pragma unroll 4
        for (int j = 0; j < 16; ++j) {
            int c4 = j * 8 + p;
            float4 a0 = f0[c4], a1 = f1[c4], a2 = f2[c4];
            ushort4 s;
            s.x = f2bf(g0 * a0.x + g1 * a1.x + g2 * a2.x);
            s.y = f2bf(g0 * a0.y + g1 * a1.y + g2 * a2.y);
            s.z = f2bf(g0 * a0.z + g1 * a1.z + g2 * a2.z);
            s.w = f2bf(g0 * a0.w + g1 * a1.w + g2 * a2.w);
            *(ushort4*)&comb[r * CS1 + c4 * 4] = s;
        }
        const unsigned short* Pb = P + (size_t)b * MM * NC;
        if (p < 4) {
            for (int q = p; q < 32; q += 4) {
                unsigned short v = 0;
                if (q < NC)
                    v = f2bf((bf2f(Pb[(size_t)j0 * NC + q]) + bf2f(Pb[(size_t)j1 * NC + q]) +
                              bf2f(Pb[(size_t)j2 * NC + q])) * (1.0f / 3.0f));
                comb[r * CS1 + 512 + q] = v;
            }
        }
    }
    __syncthreads();

    // ---- layer 1 ----
    {
        const int n0 = wv * 64;
        f4 acc1[2][4];
#pragma unroll
        for (int rt = 0; rt < 2; ++rt)
#pragma unroll
            for (int c = 0; c < 4; ++c) acc1[rt][c] = (f4){0.f, 0.f, 0.f, 0.f};
        for (int kb = 0; kb < KT1; ++kb) {
            s8 a0 = *(const s8*)&comb[l15 * CS1 + kb * 32 + quad * 8];
            s8 a1 = *(const s8*)&comb[(l15 + 16) * CS1 + kb * 32 + quad * 8];
            s8 bfr[4];
#pragma unroll
            for (int c = 0; c < 4; ++c)
                bfr[c] = *(const s8*)&w1p[((size_t)(kb * H2 + n0 + c * 16 + l15)) * 32 + quad * 8];
#pragma unroll
            for (int c = 0; c < 4; ++c) {
                acc1[0][c] = __builtin_amdgcn_mfma_f32_16x16x32_bf16(a0, bfr[c], acc1[0][c], 0, 0, 0);
                acc1[1][c] = __builtin_amdgcn_mfma_f32_16x16x32_bf16(a1, bfr[c], acc1[1][c], 0, 0, 0);
            }
        }
#pragma unroll
        for (int c = 0; c < 4; ++c) {
            int ccol = n0 + c * 16 + l15;
            float bias = b1g[ccol];
#pragma unroll
            for (int rt = 0; rt < 2; ++rt)
#pragma unroll
                for (int i = 0; i < 4; ++i) {
                    int rr = rt * 16 + quad * 4 + i;
                    hid[rr * HS + ccol] = f2bf(fmaxf(acc1[rt][c][i] + bias, 0.0f));
                }
        }
    }
    __syncthreads();

    // ---- layer 2 ----
    {
        const int m0 = wv * 128;
        f4 acc2[2][8];
#pragma unroll
        for (int rt = 0; rt < 2; ++rt)
#pragma unroll
            for (int c = 0; c < 8; ++c) acc2[rt][c] = (f4){0.f, 0.f, 0.f, 0.f};
        for (int kb = 0; kb < KT2; ++kb) {
            s8 a0 = *(const s8*)&hid[l15 * HS + kb * 32 + quad * 8];
            s8 a1 = *(const s8*)&hid[(l15 + 16) * HS + kb * 32 + quad * 8];
            s8 bfr[8];
#pragma unroll
            for (int c = 0; c < 8; ++c)
                bfr[c] = *(const s8*)&w2p[((size_t)(kb * OUTD + m0 + c * 16 + l15)) * 32 + quad * 8];
#pragma unroll
            for (int c = 0; c < 8; ++c) {
                acc2[0][c] = __builtin_amdgcn_mfma_f32_16x16x32_bf16(a0, bfr[c], acc2[0][c], 0, 0, 0);
                acc2[1][c] = __builtin_amdgcn_mfma_f32_16x16x32_bf16(a1, bfr[c], acc2[1][c], 0, 0, 0);
            }
        }
#pragma unroll
        for (int c = 0; c < 8; ++c) {
            int ccol = m0 + c * 16 + l15;
            float bias = b2g[ccol];
#pragma unroll
            for (int rt = 0; rt < 2; ++rt)
#pragma unroll
                for (int i = 0; i < 4; ++i) {
                    int rr = rt * 16 + quad * 4 + i;
                    out[(size_t)(row0 + rr) * OUTD + ccol] = acc2[rt][c][i] + bias;
                }
        }
    }
}

extern "C" void kernel_launch(void* const* d_in, const int* in_sizes, int n_in,
                              void* d_out, int out_size, void* d_ws, size_t ws_size,
                              hipStream_t stream) {
    (void)in_sizes; (void)n_in; (void)out_size; (void)ws_size;
    const float* src_points   = (const float*)d_in[0];
    const float* tgt_points   = (const float*)d_in[1];
    const float* src_features = (const float*)d_in[2];
    const float* w_sem1 = (const float*)d_in[3];
    const float* b_sem1 = (const float*)d_in[4];
    const float* w_sem2 = (const float*)d_in[5];
    const float* b_sem2 = (const float*)d_in[6];
    const float* w_up1  = (const float*)d_in[7];
    const float* b_up1  = (const float*)d_in[8];
    const float* w_up2  = (const float*)d_in[9];
    const float* b_up2  = (const float*)d_in[10];

    float* out    = (float*)d_out;
    float* ups    = out;
    float* logits = out + (size_t)BB * NN * OUTD;

    // workspace layout (< 4 MiB)
    char* w = (char*)d_ws;
    float4* sp4 = (float4*)w;                          w += (size_t)BB * MM * 16;
    float* pd2  = (float*)w;                           w += (size_t)BB * NN * SPLIT * KNN * 4;
    unsigned short* P    = (unsigned short*)w;         w += (size_t)BB * MM * NC * 2;
    unsigned short* pidx = (unsigned short*)w;         w += (size_t)BB * NN * SPLIT * KNN * 2;
    unsigned short* w1p  = (unsigned short*)w;         w += (size_t)KT1 * H2 * 32 * 2;
    unsigned short* w2p  = (unsigned short*)w;         w += (size_t)KT2 * OUTD * 32 * 2;
    unsigned short* ws1p = (unsigned short*)w;         w += (size_t)SKT1 * H1 * 32 * 2;
    unsigned short* ws2p = (unsigned short*)w;         w += (size_t)SKT2 * 32 * 32 * 2;

    prep_kernel<<<dim3((KT1 * H2 * 32 + 255) / 256), dim3(256), 0, stream>>>(
        src_points, w_up1, w_up2, w_sem1, w_sem2, sp4, w1p, w2p, ws1p, ws2p);
    sem_kernel<<<dim3(BB * MM / 32), dim3(256), 0, stream>>>(
        src_features, ws1p, ws2p, b_sem1, b_sem2, logits, P);
    knn_partial<<<dim3(BB * NN / 256, SPLIT), dim3(256), 0, stream>>>(
        sp4, tgt_points, pd2, pidx);
    up_kernel<<<dim3(BB * NN / RR), dim3(256), 0, stream>>>(
        src_features, P, pd2, pidx, tgt_points, w1p, w2p, b_up1, b_up2, ups);
}